// Round 5
// baseline (641.575 us; speedup 1.0000x reference)
//
#include <hip/hip_runtime.h>
#include <math.h>

#define N_NODES 100000
#define N_EDGES 3200000
#define NPB 256                              // nodes per bucket
#define NBUCK ((N_NODES + NPB - 1) / NPB)    // 391
#define NPW 8                                // nodes per wave (fused kernels)

typedef unsigned short ushort_t;

static __device__ __forceinline__ float bf2f(ushort_t u) {
    return __uint_as_float(((unsigned int)u) << 16);
}
static __device__ __forceinline__ ushort_t f2bf(float f) {
    unsigned int x = __float_as_uint(f);
    unsigned int lsb = (x >> 16) & 1u;
    x += 0x7fffu + lsb;  // round-to-nearest-even
    return (ushort_t)(x >> 16);
}

// ---- pass A: bucket histogram (LDS-aggregated) ----
__global__ void bucket_hist_kernel(const int* __restrict__ col, int* __restrict__ bucketCnt) {
    __shared__ int h[NBUCK];
    for (int t = threadIdx.x; t < NBUCK; t += 256) h[t] = 0;
    __syncthreads();
    for (int e = blockIdx.x * 256 + threadIdx.x; e < N_EDGES; e += gridDim.x * 256)
        atomicAdd(&h[col[e] >> 8], 1);
    __syncthreads();
    for (int t = threadIdx.x; t < NBUCK; t += 256)
        if (h[t]) atomicAdd(&bucketCnt[t], h[t]);
}

// ---- pass B: scan bucket counts -> bucketOff; init bcursor ----
__global__ void bucket_scan_kernel(const int* __restrict__ bucketCnt, int* __restrict__ bucketOff,
                                   int* __restrict__ bcursor) {
    __shared__ int tmp[512];
    int tx = threadIdx.x;
    int v = (tx < NBUCK) ? bucketCnt[tx] : 0;
    tmp[tx] = v;
    __syncthreads();
    for (int off = 1; off < 512; off <<= 1) {
        int t = (tx >= off) ? tmp[tx - off] : 0;
        __syncthreads();
        if (tx >= off) tmp[tx] += t;
        __syncthreads();
    }
    if (tx < NBUCK) {
        int o = tmp[tx] - v;
        bucketOff[tx] = o;
        bcursor[tx] = o;
    }
}

// ---- pass C: bin edges by bucket (block-aggregated append) ----
__global__ void bin_kernel(const int* __restrict__ row, const int* __restrict__ col,
                           int* __restrict__ bcursor, int2* __restrict__ tmpE) {
    __shared__ int hist[NBUCK];
    __shared__ int chunkOff[NBUCK];
    int tx = threadIdx.x;
    for (int t = tx; t < NBUCK; t += 512) hist[t] = 0;
    __syncthreads();
    int base = blockIdx.x * 4096;
    int myc[8], myr[8], myrank[8];
#pragma unroll 8
    for (int k = 0; k < 8; ++k) {
        int idx = base + k * 512 + tx;
        bool valid = idx < N_EDGES;
        int c = valid ? col[idx] : 0;
        int r = valid ? row[idx] : 0;
        myc[k] = c;
        myr[k] = r;
        myrank[k] = valid ? atomicAdd(&hist[c >> 8], 1) : 0;
    }
    __syncthreads();
    for (int t = tx; t < NBUCK; t += 512) {
        int hv = hist[t];
        chunkOff[t] = hv ? atomicAdd(&bcursor[t], hv) : 0;
    }
    __syncthreads();
#pragma unroll 8
    for (int k = 0; k < 8; ++k) {
        int idx = base + k * 512 + tx;
        if (idx < N_EDGES) {
            int pos = chunkOff[myc[k] >> 8] + myrank[k];
            tmpE[pos] = make_int2(myr[k], myc[k]);
        }
    }
}

// ---- pass D: per-bucket CSR: starts, isq, edgeRow; + npos reduction ----
__global__ void csr_kernel(const int2* __restrict__ tmpE, const int* __restrict__ bucketOff,
                           const int* __restrict__ bucketCnt, int* __restrict__ starts,
                           int* __restrict__ edgeRow, float* __restrict__ isq,
                           const float* __restrict__ labels, float* __restrict__ npos) {
    __shared__ int scnt[NPB];
    __shared__ int sscan[NPB];
    __shared__ int scur[NPB];
    __shared__ float red[NPB];
    int b = blockIdx.x;
    int lo = b * NPB;
    int nn = N_NODES - lo;
    if (nn > NPB) nn = NPB;
    int base = bucketOff[b];
    int ecnt = bucketCnt[b];
    int tx = threadIdx.x;
    scnt[tx] = 0;
    __syncthreads();
    for (int t = tx; t < ecnt; t += NPB) atomicAdd(&scnt[tmpE[base + t].y - lo], 1);
    __syncthreads();
    int v = scnt[tx];
    sscan[tx] = v;
    __syncthreads();
    for (int off = 1; off < NPB; off <<= 1) {
        int t = (tx >= off) ? sscan[tx - off] : 0;
        __syncthreads();
        if (tx >= off) sscan[tx] += t;
        __syncthreads();
    }
    int excl = sscan[tx] - v;
    scur[tx] = excl;
    float lab = 0.0f;
    if (tx < nn) {
        starts[lo + tx] = base + excl;
        isq[lo + tx] = rsqrtf((float)v + 1.0f);
        lab = labels[lo + tx];
    }
    if (b == NBUCK - 1 && tx == 0) starts[N_NODES] = N_EDGES;
    red[tx] = lab;
    __syncthreads();
    for (int s = NPB / 2; s > 0; s >>= 1) {
        if (tx < s) red[tx] += red[tx + s];
        __syncthreads();
    }
    if (tx == 0) atomicAdd(npos, red[0]);
    for (int t = tx; t < ecnt; t += NPB) {
        int2 rc = tmpE[base + t];
        int p = atomicAdd(&scur[rc.y - lo], 1);
        edgeRow[base + p] = rc.x;
    }
}

// ---- pass E: edgeRN[t] = {row, isq[row]*isq[owner]} (overwrites tmpE region) ----
__global__ void norm_fill_kernel(const int* __restrict__ starts, const int* __restrict__ edgeRow,
                                 const float* __restrict__ isq, int2* __restrict__ edgeRN) {
    int w = threadIdx.x >> 6;
    int lane = threadIdx.x & 63;
    int nodeBase = blockIdx.x * (4 * NPW) + w * NPW;
    for (int i = 0; i < NPW; ++i) {
        int node = __builtin_amdgcn_readfirstlane(nodeBase + i);
        int s = starts[node];
        int e = starts[node + 1];
        float si = isq[node];
        for (int t = s + lane; t < e; t += 64) {
            int r = edgeRow[t];
            edgeRN[t] = make_int2(r, __float_as_int(isq[r] * si));
        }
    }
}

// ---- x (fp32 N*32) -> bf16 table ----
__global__ void xcast_kernel(const float* __restrict__ x, ushort_t* __restrict__ xbf) {
    int i = blockIdx.x * 256 + threadIdx.x;  // group of 4
    if (i < (N_NODES * 32) / 4) {
        float4 v = ((const float4*)x)[i];
        ushort4 o;
        o.x = f2bf(v.x); o.y = f2bf(v.y); o.z = f2bf(v.z); o.w = f2bf(v.w);
        ((ushort4*)xbf)[i] = o;
    }
}

// ---- layer 1 fused: agg(x)[32] -> @W[32x64]+b -> relu -> bf16 h ----
// scalar edge metadata; 2 edges/iter (half-wave each); epilogue b128 on W^T
__global__ void fused32_kernel(const int* __restrict__ starts, const int2* __restrict__ edgeRN,
                               const ushort_t* __restrict__ xbf, const float* __restrict__ isq,
                               const float* __restrict__ W, const float* __restrict__ bias,
                               ushort_t* __restrict__ hout) {
    __shared__ float sWT[64 * 36];  // sWT[j*36+k] = W[k*64+j]; pad 36: 16B-aligned rows
    __shared__ float sAgg[4][32];
    for (int t = threadIdx.x; t < 32 * 64; t += 256) {
        int k = t >> 6, j = t & 63;
        sWT[j * 36 + k] = W[t];
    }
    __syncthreads();
    int w = threadIdx.x >> 6;
    int lane = threadIdx.x & 63;
    int f = lane & 31, half = lane >> 5;
    int nodeBase = blockIdx.x * (4 * NPW) + w * NPW;
    for (int i = 0; i < NPW; ++i) {
        int node = __builtin_amdgcn_readfirstlane(nodeBase + i);
        int sU = starts[node];
        int eU = starts[node + 1];
        float si = isq[node];
        float acc = 0.0f;
        int j = sU;
        for (; j + 2 <= eU; j += 2) {
            int2 rn0 = edgeRN[j];
            int2 rn1 = edgeRN[j + 1];
            int r = half ? rn1.x : rn0.x;
            float n = __int_as_float(half ? rn1.y : rn0.y);
            acc = fmaf(bf2f(xbf[(size_t)r * 32 + f]), n, acc);
        }
        if (j < eU) {
            int2 rn0 = edgeRN[j];
            float n = half ? 0.0f : __int_as_float(rn0.y);
            acc = fmaf(bf2f(xbf[(size_t)rn0.x * 32 + f]), n, acc);
        }
        float other = __shfl(acc, f + 32);
        if (half == 0) {
            acc += other;
            acc = fmaf(bf2f(xbf[(size_t)node * 32 + f]), si * si, acc);  // self-loop
            sAgg[w][f] = acc;
        }
        float o = bias[lane];
#pragma unroll
        for (int k = 0; k < 32; k += 4) {
            float4 wv = *(const float4*)&sWT[lane * 36 + k];
            float4 av = *(const float4*)&sAgg[w][k];
            o = fmaf(av.x, wv.x, o);
            o = fmaf(av.y, wv.y, o);
            o = fmaf(av.z, wv.z, o);
            o = fmaf(av.w, wv.w, o);
        }
        o = o > 0.0f ? o : 0.0f;
        hout[(size_t)node * 64 + lane] = f2bf(o);
    }
}

// ---- layers 2/3 fused: agg(h)[64] -> @W[64x64]+b -> relu -> bf16 h ----
__global__ void fused64_kernel(const int* __restrict__ starts, const int2* __restrict__ edgeRN,
                               const ushort_t* __restrict__ hin, const float* __restrict__ isq,
                               const float* __restrict__ W, const float* __restrict__ bias,
                               ushort_t* __restrict__ hout) {
    __shared__ float sWT[64 * 68];  // sWT[j*68+k] = W[k*64+j]; pad 68: 16B-aligned rows
    __shared__ float sAgg[4][64];
    for (int t = threadIdx.x; t < 64 * 64; t += 256) {
        int k = t >> 6, j = t & 63;
        sWT[j * 68 + k] = W[t];
    }
    __syncthreads();
    int w = threadIdx.x >> 6;
    int lane = threadIdx.x & 63;
    int nodeBase = blockIdx.x * (4 * NPW) + w * NPW;
    for (int i = 0; i < NPW; ++i) {
        int node = __builtin_amdgcn_readfirstlane(nodeBase + i);
        int sU = starts[node];
        int eU = starts[node + 1];
        float si = isq[node];
        float acc = bf2f(hin[(size_t)node * 64 + lane]) * (si * si);  // self-loop
        float acc2 = 0.0f;
        int j = sU;
        for (; j + 2 <= eU; j += 2) {
            int2 rn0 = edgeRN[j];
            int2 rn1 = edgeRN[j + 1];
            acc = fmaf(bf2f(hin[(size_t)rn0.x * 64 + lane]), __int_as_float(rn0.y), acc);
            acc2 = fmaf(bf2f(hin[(size_t)rn1.x * 64 + lane]), __int_as_float(rn1.y), acc2);
        }
        if (j < eU) {
            int2 rn0 = edgeRN[j];
            acc = fmaf(bf2f(hin[(size_t)rn0.x * 64 + lane]), __int_as_float(rn0.y), acc);
        }
        sAgg[w][lane] = acc + acc2;
        float o = bias[lane];
#pragma unroll
        for (int k = 0; k < 64; k += 4) {
            float4 wv = *(const float4*)&sWT[lane * 68 + k];
            float4 av = *(const float4*)&sAgg[w][k];
            o = fmaf(av.x, wv.x, o);
            o = fmaf(av.y, wv.y, o);
            o = fmaf(av.z, wv.z, o);
            o = fmaf(av.w, wv.w, o);
        }
        o = o > 0.0f ? o : 0.0f;
        hout[(size_t)node * 64 + lane] = f2bf(o);
    }
}

// ---- head: relu(h@Wl1+bl1)@Wl2+bl2 -> sigmoid -> p; weighted BCE -> loss ----
__global__ void head_kernel(const ushort_t* __restrict__ h, const float* __restrict__ Wl1,
                            const float* __restrict__ bl1, const float* __restrict__ Wl2,
                            const float* __restrict__ bl2, const float* __restrict__ labels,
                            const float* __restrict__ npos, float* __restrict__ out) {
    __shared__ float sW1[64 * 8];
    __shared__ float sb1[8];
    __shared__ float sW2[8];
    for (int t = threadIdx.x; t < 512; t += 256) sW1[t] = Wl1[t];
    if (threadIdx.x < 8) {
        sb1[threadIdx.x] = bl1[threadIdx.x];
        sW2[threadIdx.x] = Wl2[threadIdx.x];
    }
    __syncthreads();
    int i = blockIdx.x * 256 + threadIdx.x;
    float contrib = 0.0f;
    if (i < N_NODES) {
        const ushort4* hr4 = (const ushort4*)(h + (size_t)i * 64);
        float a[8];
#pragma unroll
        for (int j = 0; j < 8; ++j) a[j] = sb1[j];
#pragma unroll
        for (int kb = 0; kb < 16; ++kb) {
            ushort4 v4 = hr4[kb];
            float h0 = bf2f(v4.x), h1 = bf2f(v4.y), h2 = bf2f(v4.z), h3 = bf2f(v4.w);
#pragma unroll
            for (int j = 0; j < 8; ++j) {
                a[j] = fmaf(h0, sW1[(kb * 4 + 0) * 8 + j], a[j]);
                a[j] = fmaf(h1, sW1[(kb * 4 + 1) * 8 + j], a[j]);
                a[j] = fmaf(h2, sW1[(kb * 4 + 2) * 8 + j], a[j]);
                a[j] = fmaf(h3, sW1[(kb * 4 + 3) * 8 + j], a[j]);
            }
        }
        float z = bl2[0];
#pragma unroll
        for (int j = 0; j < 8; ++j) {
            float r = a[j] > 0.0f ? a[j] : 0.0f;
            z = fmaf(r, sW2[j], z);
        }
        float p = 1.0f / (1.0f + expf(-z));
        out[1 + i] = p;
        float y = labels[i];
        float np = *npos;
        float fn = (float)N_NODES;
        float wpos = fn / (2.0f * np);
        float wneg = fn / (2.0f * (fn - np));
        float wgt = y * wpos + (1.0f - y) * wneg;
        float lse = log1pf(expf(-fabsf(z)));
        float ls_pos = fminf(z, 0.0f) - lse;
        float ls_neg = fminf(-z, 0.0f) - lse;
        float bce = -(y * ls_pos + (1.0f - y) * ls_neg);
        contrib = wgt * bce / fn;
    }
    __shared__ float red[256];
    red[threadIdx.x] = contrib;
    __syncthreads();
    for (int s = 128; s > 0; s >>= 1) {
        if (threadIdx.x < s) red[threadIdx.x] += red[threadIdx.x + s];
        __syncthreads();
    }
    if (threadIdx.x == 0) atomicAdd(out, red[0]);
}

extern "C" void kernel_launch(void* const* d_in, const int* in_sizes, int n_in,
                              void* d_out, int out_size, void* d_ws, size_t ws_size,
                              hipStream_t stream) {
    const float* x      = (const float*)d_in[0];
    const int*   ei     = (const int*)d_in[1];
    const float* labels = (const float*)d_in[2];
    const float* W1  = (const float*)d_in[3];
    const float* b1  = (const float*)d_in[4];
    const float* W2  = (const float*)d_in[5];
    const float* b2  = (const float*)d_in[6];
    const float* W3  = (const float*)d_in[7];
    const float* b3  = (const float*)d_in[8];
    const float* Wl1 = (const float*)d_in[9];
    const float* bl1 = (const float*)d_in[10];
    const float* Wl2 = (const float*)d_in[11];
    const float* bl2 = (const float*)d_in[12];

    const int* row = ei;            // edge_index[0]
    const int* col = ei + N_EDGES;  // edge_index[1]
    float* out = (float*)d_out;

    // ---- workspace layout (tmpE region is reused as edgeRN after csr) ----
    char* w = (char*)d_ws;
    int2*     tmpE    = (int2*)w;                               // E*8B
    int2*     edgeRN  = (int2*)w;                               // alias: E*8B
    int*      edgeRow = (int*)(w + (size_t)N_EDGES * 8);        // E*4B
    ushort_t* xbf     = (ushort_t*)(edgeRow + N_EDGES);         // N*32*2B
    ushort_t* hbfA    = xbf + (size_t)N_NODES * 32;             // N*64*2B
    ushort_t* hbfB    = hbfA + (size_t)N_NODES * 64;            // N*64*2B
    int*      starts  = (int*)(hbfB + (size_t)N_NODES * 64);    // N+1
    int*      bucketCnt = starts + (N_NODES + 1);               // NBUCK
    int*      bucketOff = bucketCnt + NBUCK;                    // NBUCK
    int*      bcursor   = bucketOff + NBUCK;                    // NBUCK
    float*    isq  = (float*)(bcursor + NBUCK);                 // N
    float*    npos = isq + N_NODES;                             // 1

    hipMemsetAsync(bucketCnt, 0, NBUCK * sizeof(int), stream);
    hipMemsetAsync(npos, 0, sizeof(float), stream);
    hipMemsetAsync(out, 0, sizeof(float), stream);

    const int FB = N_NODES / (4 * NPW);      // 3125 (fused/norm_fill blocks)
    const int BB = (N_EDGES + 4095) / 4096;  // 782
    const int XB = (N_NODES * 32 / 4 + 255) / 256;

    bucket_hist_kernel<<<1024, 256, 0, stream>>>(col, bucketCnt);
    bucket_scan_kernel<<<1, 512, 0, stream>>>(bucketCnt, bucketOff, bcursor);
    bin_kernel<<<BB, 512, 0, stream>>>(row, col, bcursor, tmpE);
    csr_kernel<<<NBUCK, NPB, 0, stream>>>(tmpE, bucketOff, bucketCnt, starts, edgeRow, isq,
                                          labels, npos);
    norm_fill_kernel<<<FB, 256, 0, stream>>>(starts, edgeRow, isq, edgeRN);
    xcast_kernel<<<XB, 256, 0, stream>>>(x, xbf);

    fused32_kernel<<<FB, 256, 0, stream>>>(starts, edgeRN, xbf, isq, W1, b1, hbfA);
    fused64_kernel<<<FB, 256, 0, stream>>>(starts, edgeRN, hbfA, isq, W2, b2, hbfB);
    fused64_kernel<<<FB, 256, 0, stream>>>(starts, edgeRN, hbfB, isq, W3, b3, hbfA);

    head_kernel<<<(N_NODES + 255) / 256, 256, 0, stream>>>(hbfA, Wl1, bl1, Wl2, bl2, labels,
                                                           npos, out);
}

// Round 6
// 500.070 us; speedup vs baseline: 1.2830x; 1.2830x over previous
//
#include <hip/hip_runtime.h>
#include <math.h>

#define N_NODES 100000
#define N_EDGES 3200000
#define NPB 256                              // nodes per bucket
#define NBUCK ((N_NODES + NPB - 1) / NPB)    // 391
#define NPW 4                                // nodes per wave (fused kernels)

typedef unsigned short ushort_t;

static __device__ __forceinline__ float bf2f(ushort_t u) {
    return __uint_as_float(((unsigned int)u) << 16);
}
static __device__ __forceinline__ ushort_t f2bf(float f) {
    unsigned int x = __float_as_uint(f);
    unsigned int lsb = (x >> 16) & 1u;
    x += 0x7fffu + lsb;  // round-to-nearest-even
    return (ushort_t)(x >> 16);
}

// ---- pass A: bucket histogram (LDS-aggregated) ----
__global__ void bucket_hist_kernel(const int* __restrict__ col, int* __restrict__ bucketCnt) {
    __shared__ int h[NBUCK];
    for (int t = threadIdx.x; t < NBUCK; t += 256) h[t] = 0;
    __syncthreads();
    for (int e = blockIdx.x * 256 + threadIdx.x; e < N_EDGES; e += gridDim.x * 256)
        atomicAdd(&h[col[e] >> 8], 1);
    __syncthreads();
    for (int t = threadIdx.x; t < NBUCK; t += 256)
        if (h[t]) atomicAdd(&bucketCnt[t], h[t]);
}

// ---- pass B: scan bucket counts -> bucketOff; init bcursor ----
__global__ void bucket_scan_kernel(const int* __restrict__ bucketCnt, int* __restrict__ bucketOff,
                                   int* __restrict__ bcursor) {
    __shared__ int tmp[512];
    int tx = threadIdx.x;
    int v = (tx < NBUCK) ? bucketCnt[tx] : 0;
    tmp[tx] = v;
    __syncthreads();
    for (int off = 1; off < 512; off <<= 1) {
        int t = (tx >= off) ? tmp[tx - off] : 0;
        __syncthreads();
        if (tx >= off) tmp[tx] += t;
        __syncthreads();
    }
    if (tx < NBUCK) {
        int o = tmp[tx] - v;
        bucketOff[tx] = o;
        bcursor[tx] = o;
    }
}

// ---- pass C: bin edges by bucket (block-aggregated append) ----
__global__ void bin_kernel(const int* __restrict__ row, const int* __restrict__ col,
                           int* __restrict__ bcursor, int2* __restrict__ tmpE) {
    __shared__ int hist[NBUCK];
    __shared__ int chunkOff[NBUCK];
    int tx = threadIdx.x;
    for (int t = tx; t < NBUCK; t += 512) hist[t] = 0;
    __syncthreads();
    int base = blockIdx.x * 4096;
    int myc[8], myr[8], myrank[8];
#pragma unroll 8
    for (int k = 0; k < 8; ++k) {
        int idx = base + k * 512 + tx;
        bool valid = idx < N_EDGES;
        int c = valid ? col[idx] : 0;
        int r = valid ? row[idx] : 0;
        myc[k] = c;
        myr[k] = r;
        myrank[k] = valid ? atomicAdd(&hist[c >> 8], 1) : 0;
    }
    __syncthreads();
    for (int t = tx; t < NBUCK; t += 512) {
        int hv = hist[t];
        chunkOff[t] = hv ? atomicAdd(&bcursor[t], hv) : 0;
    }
    __syncthreads();
#pragma unroll 8
    for (int k = 0; k < 8; ++k) {
        int idx = base + k * 512 + tx;
        if (idx < N_EDGES) {
            int pos = chunkOff[myc[k] >> 8] + myrank[k];
            tmpE[pos] = make_int2(myr[k], myc[k]);
        }
    }
}

// ---- pass D: per-bucket CSR: starts, isq, edgeRow; + npos reduction ----
__global__ void csr_kernel(const int2* __restrict__ tmpE, const int* __restrict__ bucketOff,
                           const int* __restrict__ bucketCnt, int* __restrict__ starts,
                           int* __restrict__ edgeRow, float* __restrict__ isq,
                           const float* __restrict__ labels, float* __restrict__ npos) {
    __shared__ int scnt[NPB];
    __shared__ int sscan[NPB];
    __shared__ int scur[NPB];
    __shared__ float red[NPB];
    int b = blockIdx.x;
    int lo = b * NPB;
    int nn = N_NODES - lo;
    if (nn > NPB) nn = NPB;
    int base = bucketOff[b];
    int ecnt = bucketCnt[b];
    int tx = threadIdx.x;
    scnt[tx] = 0;
    __syncthreads();
    for (int t = tx; t < ecnt; t += NPB) atomicAdd(&scnt[tmpE[base + t].y - lo], 1);
    __syncthreads();
    int v = scnt[tx];
    sscan[tx] = v;
    __syncthreads();
    for (int off = 1; off < NPB; off <<= 1) {
        int t = (tx >= off) ? sscan[tx - off] : 0;
        __syncthreads();
        if (tx >= off) sscan[tx] += t;
        __syncthreads();
    }
    int excl = sscan[tx] - v;
    scur[tx] = excl;
    float lab = 0.0f;
    if (tx < nn) {
        starts[lo + tx] = base + excl;
        isq[lo + tx] = rsqrtf((float)v + 1.0f);
        lab = labels[lo + tx];
    }
    if (b == NBUCK - 1 && tx == 0) starts[N_NODES] = N_EDGES;
    red[tx] = lab;
    __syncthreads();
    for (int s = NPB / 2; s > 0; s >>= 1) {
        if (tx < s) red[tx] += red[tx + s];
        __syncthreads();
    }
    if (tx == 0) atomicAdd(npos, red[0]);
    for (int t = tx; t < ecnt; t += NPB) {
        int2 rc = tmpE[base + t];
        int p = atomicAdd(&scur[rc.y - lo], 1);
        edgeRow[base + p] = rc.x;
    }
}

// ---- pass E: edgeRN[t] = {row, isq[row]*isq[owner]} (overwrites tmpE region) ----
__global__ void norm_fill_kernel(const int* __restrict__ starts, const int* __restrict__ edgeRow,
                                 const float* __restrict__ isq, int2* __restrict__ edgeRN) {
    int w = threadIdx.x >> 6;
    int lane = threadIdx.x & 63;
    int nodeBase = blockIdx.x * (4 * NPW) + w * NPW;
    for (int i = 0; i < NPW; ++i) {
        int node = nodeBase + i;
        int s = starts[node];
        int e = starts[node + 1];
        float si = isq[node];
        for (int t = s + lane; t < e; t += 64) {
            int r = edgeRow[t];
            edgeRN[t] = make_int2(r, __float_as_int(isq[r] * si));
        }
    }
}

// ---- x (fp32 N*32) -> bf16 table ----
__global__ void xcast_kernel(const float* __restrict__ x, ushort_t* __restrict__ xbf) {
    int i = blockIdx.x * 256 + threadIdx.x;  // group of 4
    if (i < (N_NODES * 32) / 4) {
        float4 v = ((const float4*)x)[i];
        ushort4 o;
        o.x = f2bf(v.x); o.y = f2bf(v.y); o.z = f2bf(v.z); o.w = f2bf(v.w);
        ((ushort4*)xbf)[i] = o;
    }
}

// ---- layer 1 fused: agg(x)[32] -> @W[32x64]+b -> relu -> bf16 h ----
// metadata via per-wave LDS broadcast; W column in packed-bf16 registers
__global__ void fused32_kernel(const int* __restrict__ starts, const int2* __restrict__ edgeRN,
                               const ushort_t* __restrict__ xbf, const float* __restrict__ isq,
                               const float* __restrict__ W, const float* __restrict__ bias,
                               ushort_t* __restrict__ hout) {
    __shared__ int2 ebuf[4][66];
    __shared__ float sAgg[4][32];
    int w = threadIdx.x >> 6;
    int lane = threadIdx.x & 63;
    int f = lane & 31, half = lane >> 5;
    // pack this lane's W column (32 entries) into 16 regs of 2x bf16
    unsigned int wpk[16];
#pragma unroll
    for (int k2 = 0; k2 < 16; ++k2) {
        float lo = W[(2 * k2) * 64 + lane];
        float hi = W[(2 * k2 + 1) * 64 + lane];
        wpk[k2] = ((unsigned int)f2bf(hi) << 16) | (unsigned int)f2bf(lo);
    }
    float bias_r = bias[lane];
    int nodeBase = blockIdx.x * (4 * NPW) + w * NPW;
    for (int i = 0; i < NPW; ++i) {
        int node = nodeBase + i;
        int sU = starts[node];
        int eU = starts[node + 1];
        float si = isq[node];
        float acc = 0.0f, acc2 = 0.0f;
        int s = sU;
        while (s < eU) {
            int cnt = eU - s;
            if (cnt > 64) cnt = 64;
            int cnt2 = (cnt + 1) & ~1;
            int2 md = (lane < cnt) ? edgeRN[s + lane] : make_int2(0, 0);
            if (lane < cnt2) ebuf[w][lane] = md;
            int j = 0;
            for (; j + 4 <= cnt2; j += 4) {  // 4 edges: 2 per half
                int4 m0 = *(const int4*)&ebuf[w][j];
                int4 m1 = *(const int4*)&ebuf[w][j + 2];
                int r0 = half ? m0.z : m0.x;
                float n0 = __int_as_float(half ? m0.w : m0.y);
                int r1 = half ? m1.z : m1.x;
                float n1 = __int_as_float(half ? m1.w : m1.y);
                acc = fmaf(bf2f(xbf[(r0 << 5) + f]), n0, acc);
                acc2 = fmaf(bf2f(xbf[(r1 << 5) + f]), n1, acc2);
            }
            if (j < cnt2) {  // 2 edges: 1 per half
                int4 m0 = *(const int4*)&ebuf[w][j];
                int r0 = half ? m0.z : m0.x;
                float n0 = __int_as_float(half ? m0.w : m0.y);
                acc = fmaf(bf2f(xbf[(r0 << 5) + f]), n0, acc);
            }
            s += cnt;
        }
        float accsum = acc + acc2;
        float other = __shfl(accsum, f + 32);
        if (half == 0) {
            accsum += other;
            accsum = fmaf(bf2f(xbf[(node << 5) + f]), si * si, accsum);  // self-loop
            sAgg[w][f] = accsum;
        }
        float o = bias_r;
#pragma unroll
        for (int q = 0; q < 8; ++q) {  // 32-dot: 8x b128 broadcast + packed W regs
            float4 av = *(const float4*)&sAgg[w][q * 4];
            unsigned int p0 = wpk[2 * q], p1 = wpk[2 * q + 1];
            o = fmaf(av.x, __uint_as_float(p0 << 16), o);
            o = fmaf(av.y, __uint_as_float(p0 & 0xffff0000u), o);
            o = fmaf(av.z, __uint_as_float(p1 << 16), o);
            o = fmaf(av.w, __uint_as_float(p1 & 0xffff0000u), o);
        }
        o = o > 0.0f ? o : 0.0f;
        hout[(node << 6) + lane] = f2bf(o);
    }
}

// ---- layers 2/3 fused: agg(h)[64] -> @W[64x64]+b -> relu -> bf16 h ----
__global__ void fused64_kernel(const int* __restrict__ starts, const int2* __restrict__ edgeRN,
                               const ushort_t* __restrict__ hin, const float* __restrict__ isq,
                               const float* __restrict__ W, const float* __restrict__ bias,
                               ushort_t* __restrict__ hout) {
    __shared__ int2 ebuf[4][66];
    __shared__ float sAgg[4][64];
    int w = threadIdx.x >> 6;
    int lane = threadIdx.x & 63;
    // pack this lane's W column (64 entries) into 32 regs of 2x bf16
    unsigned int wpk[32];
#pragma unroll
    for (int k2 = 0; k2 < 32; ++k2) {
        float lo = W[(2 * k2) * 64 + lane];
        float hi = W[(2 * k2 + 1) * 64 + lane];
        wpk[k2] = ((unsigned int)f2bf(hi) << 16) | (unsigned int)f2bf(lo);
    }
    float bias_r = bias[lane];
    int nodeBase = blockIdx.x * (4 * NPW) + w * NPW;
    for (int i = 0; i < NPW; ++i) {
        int node = nodeBase + i;
        int sU = starts[node];
        int eU = starts[node + 1];
        float si = isq[node];
        float acc = bf2f(hin[(node << 6) + lane]) * (si * si);  // self-loop
        float acc2 = 0.0f, acc3 = 0.0f, acc4 = 0.0f;
        int s = sU;
        while (s < eU) {
            int cnt = eU - s;
            if (cnt > 64) cnt = 64;
            int cnt2 = (cnt + 1) & ~1;
            int2 md = (lane < cnt) ? edgeRN[s + lane] : make_int2(0, 0);
            if (lane < cnt2) ebuf[w][lane] = md;
            int j = 0;
            for (; j + 4 <= cnt2; j += 4) {  // 4 edges via 2x b128 broadcast
                int4 m0 = *(const int4*)&ebuf[w][j];
                int4 m1 = *(const int4*)&ebuf[w][j + 2];
                acc = fmaf(bf2f(hin[(m0.x << 6) + lane]), __int_as_float(m0.y), acc);
                acc2 = fmaf(bf2f(hin[(m0.z << 6) + lane]), __int_as_float(m0.w), acc2);
                acc3 = fmaf(bf2f(hin[(m1.x << 6) + lane]), __int_as_float(m1.y), acc3);
                acc4 = fmaf(bf2f(hin[(m1.z << 6) + lane]), __int_as_float(m1.w), acc4);
            }
            if (j < cnt2) {  // remaining 2 edges
                int4 m0 = *(const int4*)&ebuf[w][j];
                acc = fmaf(bf2f(hin[(m0.x << 6) + lane]), __int_as_float(m0.y), acc);
                acc2 = fmaf(bf2f(hin[(m0.z << 6) + lane]), __int_as_float(m0.w), acc2);
            }
            s += cnt;
        }
        sAgg[w][lane] = (acc + acc2) + (acc3 + acc4);
        float o = bias_r;
#pragma unroll
        for (int q = 0; q < 16; ++q) {  // 64-dot: 16x b128 broadcast + packed W regs
            float4 av = *(const float4*)&sAgg[w][q * 4];
            unsigned int p0 = wpk[2 * q], p1 = wpk[2 * q + 1];
            o = fmaf(av.x, __uint_as_float(p0 << 16), o);
            o = fmaf(av.y, __uint_as_float(p0 & 0xffff0000u), o);
            o = fmaf(av.z, __uint_as_float(p1 << 16), o);
            o = fmaf(av.w, __uint_as_float(p1 & 0xffff0000u), o);
        }
        o = o > 0.0f ? o : 0.0f;
        hout[(node << 6) + lane] = f2bf(o);
    }
}

// ---- head: relu(h@Wl1+bl1)@Wl2+bl2 -> sigmoid -> p; weighted BCE -> loss ----
__global__ void head_kernel(const ushort_t* __restrict__ h, const float* __restrict__ Wl1,
                            const float* __restrict__ bl1, const float* __restrict__ Wl2,
                            const float* __restrict__ bl2, const float* __restrict__ labels,
                            const float* __restrict__ npos, float* __restrict__ out) {
    __shared__ float sW1[64 * 8];
    __shared__ float sb1[8];
    __shared__ float sW2[8];
    for (int t = threadIdx.x; t < 512; t += 256) sW1[t] = Wl1[t];
    if (threadIdx.x < 8) {
        sb1[threadIdx.x] = bl1[threadIdx.x];
        sW2[threadIdx.x] = Wl2[threadIdx.x];
    }
    __syncthreads();
    int i = blockIdx.x * 256 + threadIdx.x;
    float contrib = 0.0f;
    if (i < N_NODES) {
        const ushort4* hr4 = (const ushort4*)(h + (size_t)i * 64);
        float a[8];
#pragma unroll
        for (int j = 0; j < 8; ++j) a[j] = sb1[j];
#pragma unroll
        for (int kb = 0; kb < 16; ++kb) {
            ushort4 v4 = hr4[kb];
            float h0 = bf2f(v4.x), h1 = bf2f(v4.y), h2 = bf2f(v4.z), h3 = bf2f(v4.w);
#pragma unroll
            for (int j = 0; j < 8; ++j) {
                a[j] = fmaf(h0, sW1[(kb * 4 + 0) * 8 + j], a[j]);
                a[j] = fmaf(h1, sW1[(kb * 4 + 1) * 8 + j], a[j]);
                a[j] = fmaf(h2, sW1[(kb * 4 + 2) * 8 + j], a[j]);
                a[j] = fmaf(h3, sW1[(kb * 4 + 3) * 8 + j], a[j]);
            }
        }
        float z = bl2[0];
#pragma unroll
        for (int j = 0; j < 8; ++j) {
            float r = a[j] > 0.0f ? a[j] : 0.0f;
            z = fmaf(r, sW2[j], z);
        }
        float p = 1.0f / (1.0f + expf(-z));
        out[1 + i] = p;
        float y = labels[i];
        float np = *npos;
        float fn = (float)N_NODES;
        float wpos = fn / (2.0f * np);
        float wneg = fn / (2.0f * (fn - np));
        float wgt = y * wpos + (1.0f - y) * wneg;
        float lse = log1pf(expf(-fabsf(z)));
        float ls_pos = fminf(z, 0.0f) - lse;
        float ls_neg = fminf(-z, 0.0f) - lse;
        float bce = -(y * ls_pos + (1.0f - y) * ls_neg);
        contrib = wgt * bce / fn;
    }
    __shared__ float red[256];
    red[threadIdx.x] = contrib;
    __syncthreads();
    for (int s = 128; s > 0; s >>= 1) {
        if (threadIdx.x < s) red[threadIdx.x] += red[threadIdx.x + s];
        __syncthreads();
    }
    if (threadIdx.x == 0) atomicAdd(out, red[0]);
}

extern "C" void kernel_launch(void* const* d_in, const int* in_sizes, int n_in,
                              void* d_out, int out_size, void* d_ws, size_t ws_size,
                              hipStream_t stream) {
    const float* x      = (const float*)d_in[0];
    const int*   ei     = (const int*)d_in[1];
    const float* labels = (const float*)d_in[2];
    const float* W1  = (const float*)d_in[3];
    const float* b1  = (const float*)d_in[4];
    const float* W2  = (const float*)d_in[5];
    const float* b2  = (const float*)d_in[6];
    const float* W3  = (const float*)d_in[7];
    const float* b3  = (const float*)d_in[8];
    const float* Wl1 = (const float*)d_in[9];
    const float* bl1 = (const float*)d_in[10];
    const float* Wl2 = (const float*)d_in[11];
    const float* bl2 = (const float*)d_in[12];

    const int* row = ei;            // edge_index[0]
    const int* col = ei + N_EDGES;  // edge_index[1]
    float* out = (float*)d_out;

    // ---- workspace layout (tmpE region is reused as edgeRN after csr) ----
    char* w = (char*)d_ws;
    int2*     tmpE    = (int2*)w;                               // E*8B
    int2*     edgeRN  = (int2*)w;                               // alias: E*8B
    int*      edgeRow = (int*)(w + (size_t)N_EDGES * 8);        // E*4B
    ushort_t* xbf     = (ushort_t*)(edgeRow + N_EDGES);         // N*32*2B
    ushort_t* hbfA    = xbf + (size_t)N_NODES * 32;             // N*64*2B
    ushort_t* hbfB    = hbfA + (size_t)N_NODES * 64;            // N*64*2B
    int*      starts  = (int*)(hbfB + (size_t)N_NODES * 64);    // N+1
    int*      bucketCnt = starts + (N_NODES + 1);               // NBUCK
    int*      bucketOff = bucketCnt + NBUCK;                    // NBUCK
    int*      bcursor   = bucketOff + NBUCK;                    // NBUCK
    float*    isq  = (float*)(bcursor + NBUCK);                 // N
    float*    npos = isq + N_NODES;                             // 1

    hipMemsetAsync(bucketCnt, 0, NBUCK * sizeof(int), stream);
    hipMemsetAsync(npos, 0, sizeof(float), stream);
    hipMemsetAsync(out, 0, sizeof(float), stream);

    const int FB = N_NODES / (4 * NPW);      // 6250 (fused/norm_fill blocks)
    const int BB = (N_EDGES + 4095) / 4096;  // 782
    const int XB = (N_NODES * 32 / 4 + 255) / 256;

    bucket_hist_kernel<<<1024, 256, 0, stream>>>(col, bucketCnt);
    bucket_scan_kernel<<<1, 512, 0, stream>>>(bucketCnt, bucketOff, bcursor);
    bin_kernel<<<BB, 512, 0, stream>>>(row, col, bcursor, tmpE);
    csr_kernel<<<NBUCK, NPB, 0, stream>>>(tmpE, bucketOff, bucketCnt, starts, edgeRow, isq,
                                          labels, npos);
    norm_fill_kernel<<<FB, 256, 0, stream>>>(starts, edgeRow, isq, edgeRN);
    xcast_kernel<<<XB, 256, 0, stream>>>(x, xbf);

    fused32_kernel<<<FB, 256, 0, stream>>>(starts, edgeRN, xbf, isq, W1, b1, hbfA);
    fused64_kernel<<<FB, 256, 0, stream>>>(starts, edgeRN, hbfA, isq, W2, b2, hbfB);
    fused64_kernel<<<FB, 256, 0, stream>>>(starts, edgeRN, hbfB, isq, W3, b3, hbfA);

    head_kernel<<<(N_NODES + 255) / 256, 256, 0, stream>>>(hbfA, Wl1, bl1, Wl2, bl2, labels,
                                                           npos, out);
}

// Round 7
// 451.608 us; speedup vs baseline: 1.4206x; 1.1073x over previous
//
#include <hip/hip_runtime.h>
#include <math.h>

#define N_NODES 100000
#define N_EDGES 3200000
#define NPB 256                              // nodes per bucket
#define NBUCK ((N_NODES + NPB - 1) / NPB)    // 391
#define NPW 4                                // nodes per wave (fused kernels)

typedef unsigned short ushort_t;

static __device__ __forceinline__ float bf2f(ushort_t u) {
    return __uint_as_float(((unsigned int)u) << 16);
}
static __device__ __forceinline__ ushort_t f2bf(float f) {
    unsigned int x = __float_as_uint(f);
    unsigned int lsb = (x >> 16) & 1u;
    x += 0x7fffu + lsb;  // round-to-nearest-even
    return (ushort_t)(x >> 16);
}

// ---- pass A: bucket histogram (LDS-aggregated) ----
__global__ void bucket_hist_kernel(const int* __restrict__ col, int* __restrict__ bucketCnt) {
    __shared__ int h[NBUCK];
    for (int t = threadIdx.x; t < NBUCK; t += 256) h[t] = 0;
    __syncthreads();
    for (int e = blockIdx.x * 256 + threadIdx.x; e < N_EDGES; e += gridDim.x * 256)
        atomicAdd(&h[col[e] >> 8], 1);
    __syncthreads();
    for (int t = threadIdx.x; t < NBUCK; t += 256)
        if (h[t]) atomicAdd(&bucketCnt[t], h[t]);
}

// ---- pass B: scan bucket counts -> bucketOff; init bcursor ----
__global__ void bucket_scan_kernel(const int* __restrict__ bucketCnt, int* __restrict__ bucketOff,
                                   int* __restrict__ bcursor) {
    __shared__ int tmp[512];
    int tx = threadIdx.x;
    int v = (tx < NBUCK) ? bucketCnt[tx] : 0;
    tmp[tx] = v;
    __syncthreads();
    for (int off = 1; off < 512; off <<= 1) {
        int t = (tx >= off) ? tmp[tx - off] : 0;
        __syncthreads();
        if (tx >= off) tmp[tx] += t;
        __syncthreads();
    }
    if (tx < NBUCK) {
        int o = tmp[tx] - v;
        bucketOff[tx] = o;
        bcursor[tx] = o;
    }
}

// ---- pass C: bin edges by bucket (block-aggregated append) ----
__global__ void bin_kernel(const int* __restrict__ row, const int* __restrict__ col,
                           int* __restrict__ bcursor, int2* __restrict__ tmpE) {
    __shared__ int hist[NBUCK];
    __shared__ int chunkOff[NBUCK];
    int tx = threadIdx.x;
    for (int t = tx; t < NBUCK; t += 512) hist[t] = 0;
    __syncthreads();
    int base = blockIdx.x * 4096;
    int myc[8], myr[8], myrank[8];
#pragma unroll 8
    for (int k = 0; k < 8; ++k) {
        int idx = base + k * 512 + tx;
        bool valid = idx < N_EDGES;
        int c = valid ? col[idx] : 0;
        int r = valid ? row[idx] : 0;
        myc[k] = c;
        myr[k] = r;
        myrank[k] = valid ? atomicAdd(&hist[c >> 8], 1) : 0;
    }
    __syncthreads();
    for (int t = tx; t < NBUCK; t += 512) {
        int hv = hist[t];
        chunkOff[t] = hv ? atomicAdd(&bcursor[t], hv) : 0;
    }
    __syncthreads();
#pragma unroll 8
    for (int k = 0; k < 8; ++k) {
        int idx = base + k * 512 + tx;
        if (idx < N_EDGES) {
            int pos = chunkOff[myc[k] >> 8] + myrank[k];
            tmpE[pos] = make_int2(myr[k], myc[k]);
        }
    }
}

// ---- pass D: per-bucket CSR: starts, isq, edgeRow; + npos reduction ----
__global__ void csr_kernel(const int2* __restrict__ tmpE, const int* __restrict__ bucketOff,
                           const int* __restrict__ bucketCnt, int* __restrict__ starts,
                           int* __restrict__ edgeRow, float* __restrict__ isq,
                           const float* __restrict__ labels, float* __restrict__ npos) {
    __shared__ int scnt[NPB];
    __shared__ int sscan[NPB];
    __shared__ int scur[NPB];
    __shared__ float red[NPB];
    int b = blockIdx.x;
    int lo = b * NPB;
    int nn = N_NODES - lo;
    if (nn > NPB) nn = NPB;
    int base = bucketOff[b];
    int ecnt = bucketCnt[b];
    int tx = threadIdx.x;
    scnt[tx] = 0;
    __syncthreads();
    for (int t = tx; t < ecnt; t += NPB) atomicAdd(&scnt[tmpE[base + t].y - lo], 1);
    __syncthreads();
    int v = scnt[tx];
    sscan[tx] = v;
    __syncthreads();
    for (int off = 1; off < NPB; off <<= 1) {
        int t = (tx >= off) ? sscan[tx - off] : 0;
        __syncthreads();
        if (tx >= off) sscan[tx] += t;
        __syncthreads();
    }
    int excl = sscan[tx] - v;
    scur[tx] = excl;
    float lab = 0.0f;
    if (tx < nn) {
        starts[lo + tx] = base + excl;
        isq[lo + tx] = rsqrtf((float)v + 1.0f);
        lab = labels[lo + tx];
    }
    if (b == NBUCK - 1 && tx == 0) starts[N_NODES] = N_EDGES;
    red[tx] = lab;
    __syncthreads();
    for (int s = NPB / 2; s > 0; s >>= 1) {
        if (tx < s) red[tx] += red[tx + s];
        __syncthreads();
    }
    if (tx == 0) atomicAdd(npos, red[0]);
    for (int t = tx; t < ecnt; t += NPB) {
        int2 rc = tmpE[base + t];
        int p = atomicAdd(&scur[rc.y - lo], 1);
        edgeRow[base + p] = rc.x;
    }
}

// ---- pass E: edgeRN[t] = {row, isq[row]*isq[owner]} (overwrites tmpE region) ----
__global__ void norm_fill_kernel(const int* __restrict__ starts, const int* __restrict__ edgeRow,
                                 const float* __restrict__ isq, int2* __restrict__ edgeRN) {
    int w = threadIdx.x >> 6;
    int lane = threadIdx.x & 63;
    int nodeBase = blockIdx.x * (4 * NPW) + w * NPW;
    for (int i = 0; i < NPW; ++i) {
        int node = nodeBase + i;
        int s = starts[node];
        int e = starts[node + 1];
        float si = isq[node];
        for (int t = s + lane; t < e; t += 64) {
            int r = edgeRow[t];
            edgeRN[t] = make_int2(r, __float_as_int(isq[r] * si));
        }
    }
}

// ---- x (fp32 N*32) -> bf16 table ----
__global__ void xcast_kernel(const float* __restrict__ x, ushort_t* __restrict__ xbf) {
    int i = blockIdx.x * 256 + threadIdx.x;  // group of 4
    if (i < (N_NODES * 32) / 4) {
        float4 v = ((const float4*)x)[i];
        ushort4 o;
        o.x = f2bf(v.x); o.y = f2bf(v.y); o.z = f2bf(v.z); o.w = f2bf(v.w);
        ((ushort4*)xbf)[i] = o;
    }
}

// ---- layer 1 fused: agg(x)[32] -> @W[32x64]+b -> relu -> bf16 h ----
// metadata via readlane broadcast (no LDS); 2 edges/iter (one per half);
// 8-iter (16-edge) unrolled groups for deep vmem pipelining
__global__ void fused32_kernel(const int* __restrict__ starts, const int2* __restrict__ edgeRN,
                               const ushort_t* __restrict__ xbf, const float* __restrict__ isq,
                               const float* __restrict__ W, const float* __restrict__ bias,
                               ushort_t* __restrict__ hout) {
    __shared__ float sAgg[4][32];
    int w = threadIdx.x >> 6;
    int lane = threadIdx.x & 63;
    int f = lane & 31, half = lane >> 5;
    // pack this lane's W column (32 entries) into 16 regs of 2x bf16
    unsigned int wpk[16];
#pragma unroll
    for (int k2 = 0; k2 < 16; ++k2) {
        float lo = W[(2 * k2) * 64 + lane];
        float hi = W[(2 * k2 + 1) * 64 + lane];
        wpk[k2] = ((unsigned int)f2bf(hi) << 16) | (unsigned int)f2bf(lo);
    }
    float bias_r = bias[lane];
    int nodeBase = blockIdx.x * (4 * NPW) + w * NPW;
    for (int i = 0; i < NPW; ++i) {
        int node = nodeBase + i;
        int sU = starts[node];
        int eU = starts[node + 1];
        float si = isq[node];
        float acc[4] = {0.0f, 0.0f, 0.0f, 0.0f};
        int s = sU;
        while (s < eU) {
            int cnt = eU - s;
            if (cnt > 64) cnt = 64;
            int2 md = (lane < cnt) ? edgeRN[s + lane] : make_int2(0, 0);
            int npairs = (cnt + 1) >> 1;
            int ngrp = (npairs + 7) >> 3;
            for (int g = 0; g < ngrp; ++g) {
                int b0 = g << 4;  // edge base of this 16-edge group
                float nn[8];
                unsigned int vv[8];
#pragma unroll
                for (int q = 0; q < 8; ++q) {
                    int rA = __builtin_amdgcn_readlane(md.x, b0 + 2 * q);
                    int rB = __builtin_amdgcn_readlane(md.x, b0 + 2 * q + 1);
                    int nA = __builtin_amdgcn_readlane(md.y, b0 + 2 * q);
                    int nB = __builtin_amdgcn_readlane(md.y, b0 + 2 * q + 1);
                    int r = half ? rB : rA;
                    nn[q] = __int_as_float(half ? nB : nA);
                    vv[q] = xbf[(r << 5) + f];
                }
#pragma unroll
                for (int q = 0; q < 8; ++q)
                    acc[q & 3] = fmaf(bf2f((ushort_t)vv[q]), nn[q], acc[q & 3]);
            }
            s += cnt;
        }
        float accsum = (acc[0] + acc[1]) + (acc[2] + acc[3]);
        float other = __shfl(accsum, f + 32);
        if (half == 0) {
            accsum += other;
            accsum = fmaf(bf2f(xbf[(node << 5) + f]), si * si, accsum);  // self-loop
            sAgg[w][f] = accsum;
        }
        float o = bias_r;
#pragma unroll
        for (int q = 0; q < 8; ++q) {  // 32-dot: 8x b128 broadcast + packed W regs
            float4 av = *(const float4*)&sAgg[w][q * 4];
            unsigned int p0 = wpk[2 * q], p1 = wpk[2 * q + 1];
            o = fmaf(av.x, __uint_as_float(p0 << 16), o);
            o = fmaf(av.y, __uint_as_float(p0 & 0xffff0000u), o);
            o = fmaf(av.z, __uint_as_float(p1 << 16), o);
            o = fmaf(av.w, __uint_as_float(p1 & 0xffff0000u), o);
        }
        o = o > 0.0f ? o : 0.0f;
        hout[(node << 6) + lane] = f2bf(o);
    }
}

// ---- layers 2/3 fused: agg(h)[64] -> @W[64x64]+b -> relu -> bf16 h ----
// metadata via readlane broadcast; 8-edge unrolled groups, 8 gathers in flight
__global__ void fused64_kernel(const int* __restrict__ starts, const int2* __restrict__ edgeRN,
                               const ushort_t* __restrict__ hin, const float* __restrict__ isq,
                               const float* __restrict__ W, const float* __restrict__ bias,
                               ushort_t* __restrict__ hout) {
    __shared__ float sAgg[4][64];
    int w = threadIdx.x >> 6;
    int lane = threadIdx.x & 63;
    // pack this lane's W column (64 entries) into 32 regs of 2x bf16
    unsigned int wpk[32];
#pragma unroll
    for (int k2 = 0; k2 < 32; ++k2) {
        float lo = W[(2 * k2) * 64 + lane];
        float hi = W[(2 * k2 + 1) * 64 + lane];
        wpk[k2] = ((unsigned int)f2bf(hi) << 16) | (unsigned int)f2bf(lo);
    }
    float bias_r = bias[lane];
    int nodeBase = blockIdx.x * (4 * NPW) + w * NPW;
    for (int i = 0; i < NPW; ++i) {
        int node = nodeBase + i;
        int sU = starts[node];
        int eU = starts[node + 1];
        float si = isq[node];
        float acc[4];
        acc[0] = bf2f(hin[(node << 6) + lane]) * (si * si);  // self-loop
        acc[1] = 0.0f; acc[2] = 0.0f; acc[3] = 0.0f;
        int s = sU;
        while (s < eU) {
            int cnt = eU - s;
            if (cnt > 64) cnt = 64;
            int2 md = (lane < cnt) ? edgeRN[s + lane] : make_int2(0, 0);
            int ngrp = (cnt + 7) >> 3;
            for (int g = 0; g < ngrp; ++g) {
                int b0 = g << 3;
                float nn[8];
                unsigned int vv[8];
#pragma unroll
                for (int q = 0; q < 8; ++q) {
                    int r = __builtin_amdgcn_readlane(md.x, b0 + q);
                    nn[q] = __int_as_float(__builtin_amdgcn_readlane(md.y, b0 + q));
                    vv[q] = hin[(r << 6) + lane];
                }
#pragma unroll
                for (int q = 0; q < 8; ++q)
                    acc[q & 3] = fmaf(bf2f((ushort_t)vv[q]), nn[q], acc[q & 3]);
            }
            s += cnt;
        }
        sAgg[w][lane] = (acc[0] + acc[1]) + (acc[2] + acc[3]);
        float o = bias_r;
#pragma unroll
        for (int q = 0; q < 16; ++q) {  // 64-dot: 16x b128 broadcast + packed W regs
            float4 av = *(const float4*)&sAgg[w][q * 4];
            unsigned int p0 = wpk[2 * q], p1 = wpk[2 * q + 1];
            o = fmaf(av.x, __uint_as_float(p0 << 16), o);
            o = fmaf(av.y, __uint_as_float(p0 & 0xffff0000u), o);
            o = fmaf(av.z, __uint_as_float(p1 << 16), o);
            o = fmaf(av.w, __uint_as_float(p1 & 0xffff0000u), o);
        }
        o = o > 0.0f ? o : 0.0f;
        hout[(node << 6) + lane] = f2bf(o);
    }
}

// ---- head: relu(h@Wl1+bl1)@Wl2+bl2 -> sigmoid -> p; weighted BCE -> loss ----
__global__ void head_kernel(const ushort_t* __restrict__ h, const float* __restrict__ Wl1,
                            const float* __restrict__ bl1, const float* __restrict__ Wl2,
                            const float* __restrict__ bl2, const float* __restrict__ labels,
                            const float* __restrict__ npos, float* __restrict__ out) {
    __shared__ float sW1[64 * 8];
    __shared__ float sb1[8];
    __shared__ float sW2[8];
    for (int t = threadIdx.x; t < 512; t += 256) sW1[t] = Wl1[t];
    if (threadIdx.x < 8) {
        sb1[threadIdx.x] = bl1[threadIdx.x];
        sW2[threadIdx.x] = Wl2[threadIdx.x];
    }
    __syncthreads();
    int i = blockIdx.x * 256 + threadIdx.x;
    float contrib = 0.0f;
    if (i < N_NODES) {
        const ushort4* hr4 = (const ushort4*)(h + (size_t)i * 64);
        float a[8];
#pragma unroll
        for (int j = 0; j < 8; ++j) a[j] = sb1[j];
#pragma unroll
        for (int kb = 0; kb < 16; ++kb) {
            ushort4 v4 = hr4[kb];
            float h0 = bf2f(v4.x), h1 = bf2f(v4.y), h2 = bf2f(v4.z), h3 = bf2f(v4.w);
#pragma unroll
            for (int j = 0; j < 8; ++j) {
                a[j] = fmaf(h0, sW1[(kb * 4 + 0) * 8 + j], a[j]);
                a[j] = fmaf(h1, sW1[(kb * 4 + 1) * 8 + j], a[j]);
                a[j] = fmaf(h2, sW1[(kb * 4 + 2) * 8 + j], a[j]);
                a[j] = fmaf(h3, sW1[(kb * 4 + 3) * 8 + j], a[j]);
            }
        }
        float z = bl2[0];
#pragma unroll
        for (int j = 0; j < 8; ++j) {
            float r = a[j] > 0.0f ? a[j] : 0.0f;
            z = fmaf(r, sW2[j], z);
        }
        float p = 1.0f / (1.0f + expf(-z));
        out[1 + i] = p;
        float y = labels[i];
        float np = *npos;
        float fn = (float)N_NODES;
        float wpos = fn / (2.0f * np);
        float wneg = fn / (2.0f * (fn - np));
        float wgt = y * wpos + (1.0f - y) * wneg;
        float lse = log1pf(expf(-fabsf(z)));
        float ls_pos = fminf(z, 0.0f) - lse;
        float ls_neg = fminf(-z, 0.0f) - lse;
        float bce = -(y * ls_pos + (1.0f - y) * ls_neg);
        contrib = wgt * bce / fn;
    }
    __shared__ float red[256];
    red[threadIdx.x] = contrib;
    __syncthreads();
    for (int s = 128; s > 0; s >>= 1) {
        if (threadIdx.x < s) red[threadIdx.x] += red[threadIdx.x + s];
        __syncthreads();
    }
    if (threadIdx.x == 0) atomicAdd(out, red[0]);
}

extern "C" void kernel_launch(void* const* d_in, const int* in_sizes, int n_in,
                              void* d_out, int out_size, void* d_ws, size_t ws_size,
                              hipStream_t stream) {
    const float* x      = (const float*)d_in[0];
    const int*   ei     = (const int*)d_in[1];
    const float* labels = (const float*)d_in[2];
    const float* W1  = (const float*)d_in[3];
    const float* b1  = (const float*)d_in[4];
    const float* W2  = (const float*)d_in[5];
    const float* b2  = (const float*)d_in[6];
    const float* W3  = (const float*)d_in[7];
    const float* b3  = (const float*)d_in[8];
    const float* Wl1 = (const float*)d_in[9];
    const float* bl1 = (const float*)d_in[10];
    const float* Wl2 = (const float*)d_in[11];
    const float* bl2 = (const float*)d_in[12];

    const int* row = ei;            // edge_index[0]
    const int* col = ei + N_EDGES;  // edge_index[1]
    float* out = (float*)d_out;

    // ---- workspace layout (tmpE region is reused as edgeRN after csr) ----
    char* w = (char*)d_ws;
    int2*     tmpE    = (int2*)w;                               // E*8B
    int2*     edgeRN  = (int2*)w;                               // alias: E*8B
    int*      edgeRow = (int*)(w + (size_t)N_EDGES * 8);        // E*4B
    ushort_t* xbf     = (ushort_t*)(edgeRow + N_EDGES);         // N*32*2B
    ushort_t* hbfA    = xbf + (size_t)N_NODES * 32;             // N*64*2B
    ushort_t* hbfB    = hbfA + (size_t)N_NODES * 64;            // N*64*2B
    int*      starts  = (int*)(hbfB + (size_t)N_NODES * 64);    // N+1
    int*      bucketCnt = starts + (N_NODES + 1);               // NBUCK
    int*      bucketOff = bucketCnt + NBUCK;                    // NBUCK
    int*      bcursor   = bucketOff + NBUCK;                    // NBUCK
    float*    isq  = (float*)(bcursor + NBUCK);                 // N
    float*    npos = isq + N_NODES;                             // 1

    hipMemsetAsync(bucketCnt, 0, NBUCK * sizeof(int), stream);
    hipMemsetAsync(npos, 0, sizeof(float), stream);
    hipMemsetAsync(out, 0, sizeof(float), stream);

    const int FB = N_NODES / (4 * NPW);      // 6250 (fused/norm_fill blocks)
    const int BB = (N_EDGES + 4095) / 4096;  // 782
    const int XB = (N_NODES * 32 / 4 + 255) / 256;

    bucket_hist_kernel<<<1024, 256, 0, stream>>>(col, bucketCnt);
    bucket_scan_kernel<<<1, 512, 0, stream>>>(bucketCnt, bucketOff, bcursor);
    bin_kernel<<<BB, 512, 0, stream>>>(row, col, bcursor, tmpE);
    csr_kernel<<<NBUCK, NPB, 0, stream>>>(tmpE, bucketOff, bucketCnt, starts, edgeRow, isq,
                                          labels, npos);
    norm_fill_kernel<<<FB, 256, 0, stream>>>(starts, edgeRow, isq, edgeRN);
    xcast_kernel<<<XB, 256, 0, stream>>>(x, xbf);

    fused32_kernel<<<FB, 256, 0, stream>>>(starts, edgeRN, xbf, isq, W1, b1, hbfA);
    fused64_kernel<<<FB, 256, 0, stream>>>(starts, edgeRN, hbfA, isq, W2, b2, hbfB);
    fused64_kernel<<<FB, 256, 0, stream>>>(starts, edgeRN, hbfB, isq, W3, b3, hbfA);

    head_kernel<<<(N_NODES + 255) / 256, 256, 0, stream>>>(hbfA, Wl1, bl1, Wl2, bl2, labels,
                                                           npos, out);
}

// Round 8
// 435.410 us; speedup vs baseline: 1.4735x; 1.0372x over previous
//
#include <hip/hip_runtime.h>
#include <math.h>

#define N_NODES 100000
#define N_EDGES 3200000
#define NPB 256                              // nodes per bucket
#define NBUCK ((N_NODES + NPB - 1) / NPB)    // 391
#define NPW 4                                // nodes per wave (fused kernels)

typedef unsigned short ushort_t;

static __device__ __forceinline__ float bf2f(ushort_t u) {
    return __uint_as_float(((unsigned int)u) << 16);
}
static __device__ __forceinline__ unsigned int f2bf_u(float f) {
    unsigned int x = __float_as_uint(f);
    unsigned int lsb = (x >> 16) & 1u;
    x += 0x7fffu + lsb;  // round-to-nearest-even
    return x >> 16;
}
static __device__ __forceinline__ ushort_t f2bf(float f) { return (ushort_t)f2bf_u(f); }

// ---- pass A: bucket histogram (LDS-aggregated) ----
__global__ void bucket_hist_kernel(const int* __restrict__ col, int* __restrict__ bucketCnt) {
    __shared__ int h[NBUCK];
    for (int t = threadIdx.x; t < NBUCK; t += 256) h[t] = 0;
    __syncthreads();
    for (int e = blockIdx.x * 256 + threadIdx.x; e < N_EDGES; e += gridDim.x * 256)
        atomicAdd(&h[col[e] >> 8], 1);
    __syncthreads();
    for (int t = threadIdx.x; t < NBUCK; t += 256)
        if (h[t]) atomicAdd(&bucketCnt[t], h[t]);
}

// ---- pass B: scan bucket counts -> bucketOff; init bcursor ----
__global__ void bucket_scan_kernel(const int* __restrict__ bucketCnt, int* __restrict__ bucketOff,
                                   int* __restrict__ bcursor) {
    __shared__ int tmp[512];
    int tx = threadIdx.x;
    int v = (tx < NBUCK) ? bucketCnt[tx] : 0;
    tmp[tx] = v;
    __syncthreads();
    for (int off = 1; off < 512; off <<= 1) {
        int t = (tx >= off) ? tmp[tx - off] : 0;
        __syncthreads();
        if (tx >= off) tmp[tx] += t;
        __syncthreads();
    }
    if (tx < NBUCK) {
        int o = tmp[tx] - v;
        bucketOff[tx] = o;
        bcursor[tx] = o;
    }
}

// ---- pass C: bin edges by bucket (block-aggregated append) ----
__global__ void bin_kernel(const int* __restrict__ row, const int* __restrict__ col,
                           int* __restrict__ bcursor, int2* __restrict__ tmpE) {
    __shared__ int hist[NBUCK];
    __shared__ int chunkOff[NBUCK];
    int tx = threadIdx.x;
    for (int t = tx; t < NBUCK; t += 512) hist[t] = 0;
    __syncthreads();
    int base = blockIdx.x * 4096;
    int myc[8], myr[8], myrank[8];
#pragma unroll 8
    for (int k = 0; k < 8; ++k) {
        int idx = base + k * 512 + tx;
        bool valid = idx < N_EDGES;
        int c = valid ? col[idx] : 0;
        int r = valid ? row[idx] : 0;
        myc[k] = c;
        myr[k] = r;
        myrank[k] = valid ? atomicAdd(&hist[c >> 8], 1) : 0;
    }
    __syncthreads();
    for (int t = tx; t < NBUCK; t += 512) {
        int hv = hist[t];
        chunkOff[t] = hv ? atomicAdd(&bcursor[t], hv) : 0;
    }
    __syncthreads();
#pragma unroll 8
    for (int k = 0; k < 8; ++k) {
        int idx = base + k * 512 + tx;
        if (idx < N_EDGES) {
            int pos = chunkOff[myc[k] >> 8] + myrank[k];
            tmpE[pos] = make_int2(myr[k], myc[k]);
        }
    }
}

// ---- pass D: per-bucket CSR: starts, isq, edgeRow; + npos reduction ----
__global__ void csr_kernel(const int2* __restrict__ tmpE, const int* __restrict__ bucketOff,
                           const int* __restrict__ bucketCnt, int* __restrict__ starts,
                           int* __restrict__ edgeRow, float* __restrict__ isq,
                           const float* __restrict__ labels, float* __restrict__ npos) {
    __shared__ int scnt[NPB];
    __shared__ int sscan[NPB];
    __shared__ int scur[NPB];
    __shared__ float red[NPB];
    int b = blockIdx.x;
    int lo = b * NPB;
    int nn = N_NODES - lo;
    if (nn > NPB) nn = NPB;
    int base = bucketOff[b];
    int ecnt = bucketCnt[b];
    int tx = threadIdx.x;
    scnt[tx] = 0;
    __syncthreads();
    for (int t = tx; t < ecnt; t += NPB) atomicAdd(&scnt[tmpE[base + t].y - lo], 1);
    __syncthreads();
    int v = scnt[tx];
    sscan[tx] = v;
    __syncthreads();
    for (int off = 1; off < NPB; off <<= 1) {
        int t = (tx >= off) ? sscan[tx - off] : 0;
        __syncthreads();
        if (tx >= off) sscan[tx] += t;
        __syncthreads();
    }
    int excl = sscan[tx] - v;
    scur[tx] = excl;
    float lab = 0.0f;
    if (tx < nn) {
        starts[lo + tx] = base + excl;
        isq[lo + tx] = rsqrtf((float)v + 1.0f);
        lab = labels[lo + tx];
    }
    if (b == NBUCK - 1 && tx == 0) starts[N_NODES] = N_EDGES;
    red[tx] = lab;
    __syncthreads();
    for (int s = NPB / 2; s > 0; s >>= 1) {
        if (tx < s) red[tx] += red[tx + s];
        __syncthreads();
    }
    if (tx == 0) atomicAdd(npos, red[0]);
    for (int t = tx; t < ecnt; t += NPB) {
        int2 rc = tmpE[base + t];
        int p = atomicAdd(&scur[rc.y - lo], 1);
        edgeRow[base + p] = rc.x;
    }
}

// ---- pass E: edgeRN[t] = {row, isq[row]*isq[owner]} (overwrites tmpE region) ----
__global__ void norm_fill_kernel(const int* __restrict__ starts, const int* __restrict__ edgeRow,
                                 const float* __restrict__ isq, int2* __restrict__ edgeRN) {
    int w = threadIdx.x >> 6;
    int lane = threadIdx.x & 63;
    int nodeBase = blockIdx.x * (4 * NPW) + w * NPW;
    for (int i = 0; i < NPW; ++i) {
        int node = nodeBase + i;
        int s = starts[node];
        int e = starts[node + 1];
        float si = isq[node];
        for (int t = s + lane; t < e; t += 64) {
            int r = edgeRow[t];
            edgeRN[t] = make_int2(r, __float_as_int(isq[r] * si));
        }
    }
}

// ---- x (fp32 N*32) -> bf16 table ----
__global__ void xcast_kernel(const float* __restrict__ x, ushort_t* __restrict__ xbf) {
    int i = blockIdx.x * 256 + threadIdx.x;  // group of 4
    if (i < (N_NODES * 32) / 4) {
        float4 v = ((const float4*)x)[i];
        ushort4 o;
        o.x = f2bf(v.x); o.y = f2bf(v.y); o.z = f2bf(v.z); o.w = f2bf(v.w);
        ((ushort4*)xbf)[i] = o;
    }
}

// ---- pack W1/W2/W3 into per-lane bf16x2 column tables ----
// layout: slot k2 in [0,80): [0,16)=W1, [16,48)=W2, [48,80)=W3; wp[k2*64+lane]
__global__ void wpack_kernel(const float* __restrict__ W1, const float* __restrict__ W2,
                             const float* __restrict__ W3, unsigned int* __restrict__ wp) {
    int t = blockIdx.x * 256 + threadIdx.x;
    if (t >= 80 * 64) return;
    int k2 = t >> 6, l = t & 63;
    const float* W;
    int kk;
    if (k2 < 16) { W = W1; kk = k2; }
    else if (k2 < 48) { W = W2; kk = k2 - 16; }
    else { W = W3; kk = k2 - 48; }
    float lo = W[(2 * kk) * 64 + l];
    float hi = W[(2 * kk + 1) * 64 + l];
    wp[t] = (f2bf_u(hi) << 16) | f2bf_u(lo);
}

// ---- layer 1 fused: agg(x)[32] -> @W[32x64]+b -> relu -> bf16 h ----
// scalar-pipe metadata (uniform s_loads), SGPR-base broadcast gathers
__global__ void fused32_kernel(const int* __restrict__ starts, const int2* __restrict__ edgeRN,
                               const ushort_t* __restrict__ xbf, const float* __restrict__ isq,
                               const unsigned int* __restrict__ wpG,
                               const float* __restrict__ bias, ushort_t* __restrict__ hout) {
    __shared__ float sAgg[4][32];
    int w = threadIdx.x >> 6;
    int lane = threadIdx.x & 63;
    int f = lane & 31, half = lane >> 5;
    unsigned int wpk[16];
#pragma unroll
    for (int k2 = 0; k2 < 16; ++k2) wpk[k2] = wpG[k2 * 64 + lane];
    float bias_r = bias[lane];
    int nodeBase = blockIdx.x * (4 * NPW) + w * NPW;
    for (int i = 0; i < NPW; ++i) {
        int node = __builtin_amdgcn_readfirstlane(nodeBase + i);
        int sU = starts[node];
        int eU = starts[node + 1];
        float si = isq[node];
        float acc[4] = {0.0f, 0.0f, 0.0f, 0.0f};
        int j = sU;
        for (; j + 8 <= eU; j += 8) {
            int2 rn[8];
#pragma unroll
            for (int q = 0; q < 8; ++q) rn[q] = edgeRN[j + q];  // uniform -> s_load
            unsigned int vv[8];
#pragma unroll
            for (int q = 0; q < 8; ++q) {
                const ushort_t* rowp = xbf + (rn[q].x << 5);     // SGPR base
                vv[q] = rowp[f];                                  // broadcast 64B row
            }
#pragma unroll
            for (int q = 0; q < 8; ++q)
                acc[q & 3] = fmaf(bf2f((ushort_t)vv[q]), __int_as_float(rn[q].y), acc[q & 3]);
        }
        for (; j < eU; ++j) {
            int2 rn = edgeRN[j];
            const ushort_t* rowp = xbf + (rn.x << 5);
            acc[0] = fmaf(bf2f(rowp[f]), __int_as_float(rn.y), acc[0]);
        }
        float accsum = (acc[0] + acc[1]) + (acc[2] + acc[3]);  // halves hold identical sums
        if (half == 0) {
            accsum = fmaf(bf2f(xbf[(node << 5) + f]), si * si, accsum);  // self-loop
            sAgg[w][f] = accsum;
        }
        float o = bias_r;
#pragma unroll
        for (int q = 0; q < 8; ++q) {  // 32-dot: 8x b128 broadcast + packed W regs
            float4 av = *(const float4*)&sAgg[w][q * 4];
            unsigned int p0 = wpk[2 * q], p1 = wpk[2 * q + 1];
            o = fmaf(av.x, __uint_as_float(p0 << 16), o);
            o = fmaf(av.y, __uint_as_float(p0 & 0xffff0000u), o);
            o = fmaf(av.z, __uint_as_float(p1 << 16), o);
            o = fmaf(av.w, __uint_as_float(p1 & 0xffff0000u), o);
        }
        o = o > 0.0f ? o : 0.0f;
        hout[(node << 6) + lane] = f2bf(o);
    }
}

// ---- layers 2/3 fused: agg(h)[64] -> @W[64x64]+b -> relu -> bf16 h ----
// scalar-pipe metadata, SGPR-base gathers: ~2-3 VALU per edge
__global__ void fused64_kernel(const int* __restrict__ starts, const int2* __restrict__ edgeRN,
                               const ushort_t* __restrict__ hin, const float* __restrict__ isq,
                               const unsigned int* __restrict__ wpG,
                               const float* __restrict__ bias, ushort_t* __restrict__ hout) {
    __shared__ float sAgg[4][64];
    int w = threadIdx.x >> 6;
    int lane = threadIdx.x & 63;
    unsigned int wpk[32];
#pragma unroll
    for (int k2 = 0; k2 < 32; ++k2) wpk[k2] = wpG[k2 * 64 + lane];
    float bias_r = bias[lane];
    int nodeBase = blockIdx.x * (4 * NPW) + w * NPW;
    for (int i = 0; i < NPW; ++i) {
        int node = __builtin_amdgcn_readfirstlane(nodeBase + i);
        int sU = starts[node];
        int eU = starts[node + 1];
        float si = isq[node];
        float acc[4];
        acc[0] = bf2f(hin[(node << 6) + lane]) * (si * si);  // self-loop
        acc[1] = 0.0f; acc[2] = 0.0f; acc[3] = 0.0f;
        int j = sU;
        for (; j + 8 <= eU; j += 8) {
            int2 rn[8];
#pragma unroll
            for (int q = 0; q < 8; ++q) rn[q] = edgeRN[j + q];  // uniform -> s_load
            unsigned int vv[8];
#pragma unroll
            for (int q = 0; q < 8; ++q) {
                const ushort_t* rowp = hin + (rn[q].x << 6);     // SGPR base
                vv[q] = rowp[lane];                               // coalesced 128B row
            }
#pragma unroll
            for (int q = 0; q < 8; ++q)
                acc[q & 3] = fmaf(bf2f((ushort_t)vv[q]), __int_as_float(rn[q].y), acc[q & 3]);
        }
        for (; j < eU; ++j) {
            int2 rn = edgeRN[j];
            const ushort_t* rowp = hin + (rn.x << 6);
            acc[0] = fmaf(bf2f(rowp[lane]), __int_as_float(rn.y), acc[0]);
        }
        sAgg[w][lane] = (acc[0] + acc[1]) + (acc[2] + acc[3]);
        float o = bias_r;
#pragma unroll
        for (int q = 0; q < 16; ++q) {  // 64-dot: 16x b128 broadcast + packed W regs
            float4 av = *(const float4*)&sAgg[w][q * 4];
            unsigned int p0 = wpk[2 * q], p1 = wpk[2 * q + 1];
            o = fmaf(av.x, __uint_as_float(p0 << 16), o);
            o = fmaf(av.y, __uint_as_float(p0 & 0xffff0000u), o);
            o = fmaf(av.z, __uint_as_float(p1 << 16), o);
            o = fmaf(av.w, __uint_as_float(p1 & 0xffff0000u), o);
        }
        o = o > 0.0f ? o : 0.0f;
        hout[(node << 6) + lane] = f2bf(o);
    }
}

// ---- head: relu(h@Wl1+bl1)@Wl2+bl2 -> sigmoid -> p; weighted BCE -> loss ----
__global__ void head_kernel(const ushort_t* __restrict__ h, const float* __restrict__ Wl1,
                            const float* __restrict__ bl1, const float* __restrict__ Wl2,
                            const float* __restrict__ bl2, const float* __restrict__ labels,
                            const float* __restrict__ npos, float* __restrict__ out) {
    __shared__ float sW1[64 * 8];
    __shared__ float sb1[8];
    __shared__ float sW2[8];
    for (int t = threadIdx.x; t < 512; t += 256) sW1[t] = Wl1[t];
    if (threadIdx.x < 8) {
        sb1[threadIdx.x] = bl1[threadIdx.x];
        sW2[threadIdx.x] = Wl2[threadIdx.x];
    }
    __syncthreads();
    int i = blockIdx.x * 256 + threadIdx.x;
    float contrib = 0.0f;
    if (i < N_NODES) {
        const ushort4* hr4 = (const ushort4*)(h + (size_t)i * 64);
        float a[8];
#pragma unroll
        for (int j = 0; j < 8; ++j) a[j] = sb1[j];
#pragma unroll
        for (int kb = 0; kb < 16; ++kb) {
            ushort4 v4 = hr4[kb];
            float h0 = bf2f(v4.x), h1 = bf2f(v4.y), h2 = bf2f(v4.z), h3 = bf2f(v4.w);
#pragma unroll
            for (int j = 0; j < 8; ++j) {
                a[j] = fmaf(h0, sW1[(kb * 4 + 0) * 8 + j], a[j]);
                a[j] = fmaf(h1, sW1[(kb * 4 + 1) * 8 + j], a[j]);
                a[j] = fmaf(h2, sW1[(kb * 4 + 2) * 8 + j], a[j]);
                a[j] = fmaf(h3, sW1[(kb * 4 + 3) * 8 + j], a[j]);
            }
        }
        float z = bl2[0];
#pragma unroll
        for (int j = 0; j < 8; ++j) {
            float r = a[j] > 0.0f ? a[j] : 0.0f;
            z = fmaf(r, sW2[j], z);
        }
        float p = 1.0f / (1.0f + expf(-z));
        out[1 + i] = p;
        float y = labels[i];
        float np = *npos;
        float fn = (float)N_NODES;
        float wpos = fn / (2.0f * np);
        float wneg = fn / (2.0f * (fn - np));
        float wgt = y * wpos + (1.0f - y) * wneg;
        float lse = log1pf(expf(-fabsf(z)));
        float ls_pos = fminf(z, 0.0f) - lse;
        float ls_neg = fminf(-z, 0.0f) - lse;
        float bce = -(y * ls_pos + (1.0f - y) * ls_neg);
        contrib = wgt * bce / fn;
    }
    __shared__ float red[256];
    red[threadIdx.x] = contrib;
    __syncthreads();
    for (int s = 128; s > 0; s >>= 1) {
        if (threadIdx.x < s) red[threadIdx.x] += red[threadIdx.x + s];
        __syncthreads();
    }
    if (threadIdx.x == 0) atomicAdd(out, red[0]);
}

extern "C" void kernel_launch(void* const* d_in, const int* in_sizes, int n_in,
                              void* d_out, int out_size, void* d_ws, size_t ws_size,
                              hipStream_t stream) {
    const float* x      = (const float*)d_in[0];
    const int*   ei     = (const int*)d_in[1];
    const float* labels = (const float*)d_in[2];
    const float* W1  = (const float*)d_in[3];
    const float* b1  = (const float*)d_in[4];
    const float* W2  = (const float*)d_in[5];
    const float* b2  = (const float*)d_in[6];
    const float* W3  = (const float*)d_in[7];
    const float* b3  = (const float*)d_in[8];
    const float* Wl1 = (const float*)d_in[9];
    const float* bl1 = (const float*)d_in[10];
    const float* Wl2 = (const float*)d_in[11];
    const float* bl2 = (const float*)d_in[12];

    const int* row = ei;            // edge_index[0]
    const int* col = ei + N_EDGES;  // edge_index[1]
    float* out = (float*)d_out;

    // ---- workspace layout (tmpE region is reused as edgeRN after csr) ----
    char* w = (char*)d_ws;
    int2*     tmpE    = (int2*)w;                               // E*8B
    int2*     edgeRN  = (int2*)w;                               // alias: E*8B
    int*      edgeRow = (int*)(w + (size_t)N_EDGES * 8);        // E*4B
    ushort_t* xbf     = (ushort_t*)(edgeRow + N_EDGES);         // N*32*2B
    ushort_t* hbfA    = xbf + (size_t)N_NODES * 32;             // N*64*2B
    ushort_t* hbfB    = hbfA + (size_t)N_NODES * 64;            // N*64*2B
    int*      starts  = (int*)(hbfB + (size_t)N_NODES * 64);    // N+1
    int*      bucketCnt = starts + (N_NODES + 1);               // NBUCK
    int*      bucketOff = bucketCnt + NBUCK;                    // NBUCK
    int*      bcursor   = bucketOff + NBUCK;                    // NBUCK
    float*    isq  = (float*)(bcursor + NBUCK);                 // N
    float*    npos = isq + N_NODES;                             // 1
    unsigned int* wpG = (unsigned int*)(npos + 1);              // 80*64 u32

    hipMemsetAsync(bucketCnt, 0, NBUCK * sizeof(int), stream);
    hipMemsetAsync(npos, 0, sizeof(float), stream);
    hipMemsetAsync(out, 0, sizeof(float), stream);

    const int FB = N_NODES / (4 * NPW);      // 6250 (fused/norm_fill blocks)
    const int BB = (N_EDGES + 4095) / 4096;  // 782
    const int XB = (N_NODES * 32 / 4 + 255) / 256;

    bucket_hist_kernel<<<1024, 256, 0, stream>>>(col, bucketCnt);
    bucket_scan_kernel<<<1, 512, 0, stream>>>(bucketCnt, bucketOff, bcursor);
    bin_kernel<<<BB, 512, 0, stream>>>(row, col, bcursor, tmpE);
    csr_kernel<<<NBUCK, NPB, 0, stream>>>(tmpE, bucketOff, bucketCnt, starts, edgeRow, isq,
                                          labels, npos);
    norm_fill_kernel<<<FB, 256, 0, stream>>>(starts, edgeRow, isq, edgeRN);
    xcast_kernel<<<XB, 256, 0, stream>>>(x, xbf);
    wpack_kernel<<<20, 256, 0, stream>>>(W1, W2, W3, wpG);

    fused32_kernel<<<FB, 256, 0, stream>>>(starts, edgeRN, xbf, isq, wpG, b1, hbfA);
    fused64_kernel<<<FB, 256, 0, stream>>>(starts, edgeRN, hbfA, isq, wpG + 16 * 64, b2, hbfB);
    fused64_kernel<<<FB, 256, 0, stream>>>(starts, edgeRN, hbfB, isq, wpG + 48 * 64, b3, hbfA);

    head_kernel<<<(N_NODES + 255) / 256, 256, 0, stream>>>(hbfA, Wl1, bl1, Wl2, bl2, labels,
                                                           npos, out);
}